// Round 10
// baseline (110.536 us; speedup 1.0000x reference)
//
#include <hip/hip_runtime.h>
#include <hip/hip_bf16.h>

// Problem constants: B=16, N=64, T=128, D=8, N_EMB=64, N_H=128, BN=1024,
// F_in=128, gates=512.

typedef _Float16 half8 __attribute__((ext_vector_type(8)));
typedef float f32x4 __attribute__((ext_vector_type(4)));

__device__ __forceinline__ float rcp_(float x){ return __builtin_amdgcn_rcpf(x); }
__device__ __forceinline__ float sigmoidf_(float x){ return rcp_(1.0f + __expf(-x)); }
__device__ __forceinline__ float tanhf_(float x){ return fmaf(-2.0f, rcp_(1.0f + __expf(2.0f*x)), 1.0f); }

// ---------------------------------------------------------------------------
// Kernel 1: repack W_ih/W_hh into MFMA B-fragment order, PLUS the GCN
// projection matrix W2 (block-diag [Ws|Wc] + bias row k=16) in B-frag layout.
// ---------------------------------------------------------------------------
__global__ __launch_bounds__(256) void prep_kernel(const float* __restrict__ W_ih,
                                                   const float* __restrict__ W_hh,
                                                   const float* __restrict__ Wc,
                                                   const float* __restrict__ bc,
                                                   const float* __restrict__ Ws,
                                                   const float* __restrict__ bs,
                                                   _Float16* __restrict__ wfrag,
                                                   _Float16* __restrict__ w2frag){
  int gid = blockIdx.x*256 + threadIdx.x;   // [0, 16384)
  if (gid < 512){
    int nt = gid >> 6, lane = gid & 63;
    int kq = lane >> 4, c = lane & 15;
    _Float16* dst2 = w2frag + (size_t)(nt*64 + lane)*8;
    #pragma unroll
    for (int e = 0; e < 8; e++){
      int k = 8*kq + e;
      int f = 16*nt + c;
      float v = 0.f;
      if (f < 64){
        if (k < 8) v = Ws[f*8 + k];
        else if (k == 16) v = bs[f];
      } else {
        if (k >= 8 && k < 16) v = Wc[(f-64)*8 + (k-8)];
        else if (k == 16) v = bc[f-64];
      }
      dst2[e] = (_Float16)v;
    }
  }
  int w    = gid >> 11;
  int i    = (gid >> 6) & 31;
  int lane = gid & 63;
  int src = i >> 4, kk = (i >> 2) & 3, cti = i & 3;
  int j = 16*w + 128*cti + (lane & 15);
  int kbase = 32*kk + 8*(lane >> 4);
  const float* W = src ? W_hh : W_ih;
  _Float16* dst = wfrag + (size_t)(((w*32 + i)*64 + lane) * 8);
  #pragma unroll
  for (int e = 0; e < 8; e++) dst[e] = (_Float16)W[j*128 + kbase + e];
}

// ---------------------------------------------------------------------------
// Kernel 2: GCN v3 (round-9 proven, verbatim). One WAVE per (b,t) slice.
// ---------------------------------------------------------------------------
__global__ __launch_bounds__(256) void gcn3_kernel(const float* __restrict__ x,
    const _Float16* __restrict__ w2frag, _Float16* __restrict__ feat){
  __shared__ _Float16 As16[4][64*72];
  __shared__ _Float16 zs16[4][64*40];
  __shared__ float    ns16[4][64];

  int tid = threadIdx.x;
  int wav = tid >> 6, lane = tid & 63;
  int slice = blockIdx.x*4 + wav;       // 0..2047
  int b = slice >> 7, t = slice & 127;
  int c = lane & 15, kq = lane >> 4;

  _Float16* As_w = &As16[wav][0];
  _Float16* zs_w = &zs16[wav][0];
  float*    ns_w = &ns16[wav][0];

  const float* xrow = x + ((size_t)(b*64 + lane)*128 + t)*8;
  float4 xlo = *(const float4*)xrow;
  float4 xhi = *(const float4*)(xrow + 4);
  float xr[8] = {xlo.x, xlo.y, xlo.z, xlo.w, xhi.x, xhi.y, xhi.z, xhi.w};
  {
    half8 hx;
    float nrm = 0.f;
    #pragma unroll
    for (int d = 0; d < 8; d++){ hx[d] = (_Float16)xr[d]; nrm = fmaf(xr[d], xr[d], nrm); }
    half8 h0 = (half8){0,0,0,0,0,0,0,0};
    *(half8*)(zs_w + lane*40)      = hx;
    *(half8*)(zs_w + lane*40 + 8)  = h0;
    *(half8*)(zs_w + lane*40 + 16) = h0;
    *(half8*)(zs_w + lane*40 + 24) = h0;
    ns_w[lane] = nrm;
  }

  half8 wfr[8];
  #pragma unroll
  for (int nt = 0; nt < 8; nt++)
    wfr[nt] = *(const half8*)(w2frag + (size_t)(nt*64 + lane)*8);

  half8 ga[4];
  #pragma unroll
  for (int q = 0; q < 4; q++)
    ga[q] = *(const half8*)(zs_w + (16*q + c)*40 + 8*kq);

  asm volatile("s_waitcnt lgkmcnt(0)" ::: "memory");
  {
    half8 h1 = (half8){(_Float16)1.f,0,0,0,0,0,0,0};
    *(half8*)(zs_w + lane*40 + 16) = h1;
  }

  half8 bx0, bx1;
  {
    half8 t0, t1;
    #pragma unroll
    for (int e = 0; e < 8; e++){
      t0[e] = zs_w[(8*kq + e)*40 + c];
      t1[e] = zs_w[(32 + 8*kq + e)*40 + c];
    }
    half8 h1a = (half8){(_Float16)1.f,(_Float16)1.f,(_Float16)1.f,(_Float16)1.f,
                        (_Float16)1.f,(_Float16)1.f,(_Float16)1.f,(_Float16)1.f};
    bx0 = (c == 8) ? h1a : t0;
    bx1 = (c == 8) ? h1a : t1;
  }

  f32x4 nm[4];
  float nn[4];
  #pragma unroll
  for (int q = 0; q < 4; q++){
    nm[q] = *(const f32x4*)(ns_w + 16*q + 4*kq);
    nn[q] = ns_w[16*q + c];
  }

  const f32x4 zero4 = (f32x4){0.f,0.f,0.f,0.f};
  int ediag = c - 4*kq;

  #pragma unroll
  for (int mt = 0; mt < 4; mt++){
    #pragma unroll
    for (int nt = 0; nt < 4; nt++){
      f32x4 g = __builtin_amdgcn_mfma_f32_16x16x32_f16(ga[mt], ga[nt], zero4, 0,0,0);
      #pragma unroll
      for (int e = 0; e < 4; e++){
        float d2 = nm[mt][e] + nn[nt] - 2.0f*g[e];
        float wv = __frsqrt_rn(fmaxf(d2, 1e-12f));
        if (mt == nt && e == ediag) wv = 0.f;
        As_w[(16*mt + 4*kq + e)*72 + 16*nt + c] = (_Float16)wv;
      }
    }
  }

  #pragma unroll
  for (int mt = 0; mt < 4; mt++){
    half8 aa0 = *(const half8*)(As_w + (16*mt + c)*72 + 8*kq);
    half8 aa1 = *(const half8*)(As_w + (16*mt + c)*72 + 32 + 8*kq);
    f32x4 cax = __builtin_amdgcn_mfma_f32_16x16x32_f16(aa0, bx0, zero4, 0,0,0);
    cax = __builtin_amdgcn_mfma_f32_16x16x32_f16(aa1, bx1, cax, 0,0,0);
    int bidx = ((lane & 48) | 8) << 2;
    #pragma unroll
    for (int e = 0; e < 4; e++){
      float rs = __int_as_float(__builtin_amdgcn_ds_bpermute(bidx, __float_as_int(cax[e])));
      float yv = cax[e] * rcp_(fmaxf(rs, 1e-12f));
      if (c < 8) zs_w[(16*mt + 4*kq + e)*40 + 8 + c] = (_Float16)yv;
    }
  }

  #pragma unroll
  for (int mt = 0; mt < 4; mt++){
    half8 az = *(const half8*)(zs_w + (16*mt + c)*40 + 8*kq);
    #pragma unroll
    for (int nt = 0; nt < 8; nt++){
      f32x4 pc = __builtin_amdgcn_mfma_f32_16x16x32_f16(az, wfr[nt], zero4, 0,0,0);
      #pragma unroll
      for (int e = 0; e < 4; e++){
        float v = pc[e];
        v = (v > 0.f) ? 1.0507009873554805f*v
                      : 1.7580993408473766f*(__expf(v) - 1.0f);
        feat[((size_t)t*1024 + (size_t)b*64 + 16*mt + 4*kq + e)*128 + 16*nt + c] = (_Float16)v;
      }
    }
  }
}

// ---------------------------------------------------------------------------
// Kernel 3: persistent fused LSTM v3b. Changes vs round-9 lstm3:
//  (a) h-GEMM A-tile rows grouped by sample (row r -> sample r>>2), so the
//      C-fragment's 4 elements are duplicates of sample kq -> cell reads
//      acc[0] directly, eliminating 12 cndmask/lane/step;
//  (b) each gate's K=128 MFMA chain split into two K=64 chains (depth 2);
//  (c) x-slab MFMAs issued between ds_reads and h-MFMAs (cover LDS latency).
// ---------------------------------------------------------------------------
__global__ __launch_bounds__(512, 2) void lstm3_kernel(
    const _Float16* __restrict__ wfrag, const _Float16* __restrict__ feat,
    const float* __restrict__ b_ih, const float* __restrict__ b_hh,
    float* __restrict__ out){
  int tid = threadIdx.x;
  int w = tid >> 6, l = tid & 63;
  int blk = blockIdx.x;            // 0..255
  int r = l & 15, kq = l >> 4;
  __shared__ _Float16 h_lds[2][544];   // [parity][sample*134 + hidden]

  half8 bf[32];
  const _Float16* wb = wfrag + (size_t)w*(32*64*8);
  #pragma unroll
  for (int i = 0; i < 32; i++)
    bf[i] = *(const half8*)(wb + (size_t)(i*64 + l)*8);

  f32x4 biasx4[4];
  #pragma unroll
  for (int cti = 0; cti < 4; cti++){
    int j = 16*w + 128*cti + r;
    float bv = b_ih[j] + b_hh[j];
    biasx4[cti] = (f32x4){bv, bv, bv, bv};
  }

  for (int idx = tid; idx < 544; idx += 512) h_lds[0][idx] = (_Float16)0.f;

  float cc = 0.f, hlast = 0.f;
  const f32x4 zero4 = (f32x4){0.f,0.f,0.f,0.f};

  const size_t arow_s = (size_t)(blk*4 + (r >> 2));
  const int atl = r & 3;
  // h A-tile: row r -> sample r>>2 (duplicate rows grouped by sample)
  const int habase = (r >> 2)*134 + 8*kq;

  half8 afA[4], afB[4];
  f32x4 accxA[4], accxB[4];

#define LOADAF(AF, G) {                                                       \
    int gg = (G) > 31 ? 31 : (G);                                             \
    const _Float16* fb = feat + ((size_t)(4*gg + atl)*1024 + arow_s)*128 + 8*kq; \
    AF[0] = *(const half8*)(fb);                                              \
    AF[1] = *(const half8*)(fb + 32);                                         \
    AF[2] = *(const half8*)(fb + 64);                                         \
    AF[3] = *(const half8*)(fb + 96);                                         \
  }

  LOADAF(afA, 0)
  #pragma unroll
  for (int cti = 0; cti < 4; cti++)
    accxA[cti] = __builtin_amdgcn_mfma_f32_16x16x32_f16(afA[0], bf[cti], biasx4[cti], 0,0,0);
  #pragma unroll
  for (int kk = 1; kk < 4; kk++)
    #pragma unroll
    for (int cti = 0; cti < 4; cti++)
      accxA[cti] = __builtin_amdgcn_mfma_f32_16x16x32_f16(afA[kk], bf[kk*4+cti], accxA[cti], 0,0,0);
  LOADAF(afB, 1)
  LOADAF(afA, 2)
  __syncthreads();

#define STEP3(TL, ACCU, ACCB, AFB_, GN)                                       \
  {                                                                           \
    half8 ha[4];                                                              \
    _Pragma("unroll")                                                         \
    for (int kk = 0; kk < 4; kk++)                                            \
      ha[kk] = *(const half8*)(&h_lds[(TL)&1][habase + 32*kk]);               \
    _Pragma("unroll")                                                         \
    for (int cti = 0; cti < 4; cti++){                                        \
      if ((TL) == 0)                                                          \
        ACCB[cti] = __builtin_amdgcn_mfma_f32_16x16x32_f16(AFB_[0], bf[cti], biasx4[cti], 0,0,0); \
      else                                                                    \
        ACCB[cti] = __builtin_amdgcn_mfma_f32_16x16x32_f16(AFB_[(TL)], bf[(TL)*4+cti], ACCB[cti], 0,0,0); \
    }                                                                         \
    if ((TL) == 3) LOADAF(AFB_, GN)                                           \
    f32x4 a0l, a1l, a2l, a3l, a0h, a1h, a2h, a3h;                             \
    a0l = __builtin_amdgcn_mfma_f32_16x16x32_f16(ha[0], bf[16], zero4, 0,0,0); \
    a1l = __builtin_amdgcn_mfma_f32_16x16x32_f16(ha[0], bf[17], zero4, 0,0,0); \
    a2l = __builtin_amdgcn_mfma_f32_16x16x32_f16(ha[0], bf[18], zero4, 0,0,0); \
    a3l = __builtin_amdgcn_mfma_f32_16x16x32_f16(ha[0], bf[19], zero4, 0,0,0); \
    a0h = __builtin_amdgcn_mfma_f32_16x16x32_f16(ha[2], bf[24], zero4, 0,0,0); \
    a1h = __builtin_amdgcn_mfma_f32_16x16x32_f16(ha[2], bf[25], zero4, 0,0,0); \
    a2h = __builtin_amdgcn_mfma_f32_16x16x32_f16(ha[2], bf[26], zero4, 0,0,0); \
    a3h = __builtin_amdgcn_mfma_f32_16x16x32_f16(ha[2], bf[27], zero4, 0,0,0); \
    a0l = __builtin_amdgcn_mfma_f32_16x16x32_f16(ha[1], bf[20], a0l, 0,0,0);  \
    a1l = __builtin_amdgcn_mfma_f32_16x16x32_f16(ha[1], bf[21], a1l, 0,0,0);  \
    a2l = __builtin_amdgcn_mfma_f32_16x16x32_f16(ha[1], bf[22], a2l, 0,0,0);  \
    a3l = __builtin_amdgcn_mfma_f32_16x16x32_f16(ha[1], bf[23], a3l, 0,0,0);  \
    a0h = __builtin_amdgcn_mfma_f32_16x16x32_f16(ha[3], bf[28], a0h, 0,0,0);  \
    a1h = __builtin_amdgcn_mfma_f32_16x16x32_f16(ha[3], bf[29], a1h, 0,0,0);  \
    a2h = __builtin_amdgcn_mfma_f32_16x16x32_f16(ha[3], bf[30], a2h, 0,0,0);  \
    a3h = __builtin_amdgcn_mfma_f32_16x16x32_f16(ha[3], bf[31], a3h, 0,0,0);  \
    float g0_ = a0l[0] + a0h[0] + ACCU[0][(TL)];                              \
    float g1_ = a1l[0] + a1h[0] + ACCU[1][(TL)];                              \
    float g2_ = a2l[0] + a2h[0] + ACCU[2][(TL)];                              \
    float g3_ = a3l[0] + a3h[0] + ACCU[3][(TL)];                              \
    float c_ = fmaf(sigmoidf_(g1_), cc, sigmoidf_(g0_)*tanhf_(g2_));          \
    cc = c_;                                                                  \
    float h_ = sigmoidf_(g3_)*tanhf_(c_);                                     \
    h_lds[1-((TL)&1)][kq*134 + 16*w + r] = (_Float16)h_;                      \
    if ((TL) == 3 && (GN) == 32) hlast = h_;                                  \
    asm volatile("s_waitcnt lgkmcnt(0)" ::: "memory");                        \
    __builtin_amdgcn_s_barrier();                                             \
  }

  for (int i = 0; i < 15; ++i){
    STEP3(0, accxA, accxB, afB, 0)
    STEP3(1, accxA, accxB, afB, 0)
    STEP3(2, accxA, accxB, afB, 0)
    STEP3(3, accxA, accxB, afB, 2*i+3)
    STEP3(0, accxB, accxA, afA, 0)
    STEP3(1, accxB, accxA, afA, 0)
    STEP3(2, accxB, accxA, afA, 0)
    STEP3(3, accxB, accxA, afA, 2*i+4)
  }
  STEP3(0, accxA, accxB, afB, 0)
  STEP3(1, accxA, accxB, afB, 0)
  STEP3(2, accxA, accxB, afB, 0)
  STEP3(3, accxA, accxB, afB, 33)
  STEP3(0, accxB, accxA, afA, 0)
  STEP3(1, accxB, accxA, afA, 0)
  STEP3(2, accxB, accxA, afA, 0)
  STEP3(3, accxB, accxA, afA, 32)   // t = 127: capture hlast
#undef STEP3
#undef LOADAF

  out[((size_t)blk*4 + kq)*128 + 16*w + r] = hlast;
}

// ---------------------------------------------------------------------------
extern "C" void kernel_launch(void* const* d_in, const int* in_sizes, int n_in,
                              void* d_out, int out_size, void* d_ws, size_t ws_size,
                              hipStream_t stream) {
  const float* x    = (const float*)d_in[0];
  const float* Wc   = (const float*)d_in[3];
  const float* bc   = (const float*)d_in[4];
  const float* Ws   = (const float*)d_in[5];
  const float* bs   = (const float*)d_in[6];
  const float* W_ih = (const float*)d_in[7];
  const float* W_hh = (const float*)d_in[8];
  const float* b_ih = (const float*)d_in[9];
  const float* b_hh = (const float*)d_in[10];
  float* out = (float*)d_out;

  // ws: [0,256KB) wfrag | [262144,+8KB) w2frag | [270336, +33.5MB) feat
  _Float16* wfrag  = (_Float16*)d_ws;
  _Float16* w2frag = (_Float16*)((char*)d_ws + 262144);
  _Float16* feat   = (_Float16*)((char*)d_ws + 270336);

  prep_kernel<<<64, 256, 0, stream>>>(W_ih, W_hh, Wc, bc, Ws, bs, wfrag, w2frag);
  gcn3_kernel<<<512, 256, 0, stream>>>(x, w2frag, feat);
  lstm3_kernel<<<256, 512, 0, stream>>>(wfrag, feat, b_ih, b_hh, out);
}

// Round 11
// 103.504 us; speedup vs baseline: 1.0679x; 1.0679x over previous
//
#include <hip/hip_runtime.h>
#include <hip/hip_bf16.h>

// Problem constants: B=16, N=64, T=128, D=8, N_EMB=64, N_H=128, BN=1024,
// F_in=128, gates=512.

typedef _Float16 half8 __attribute__((ext_vector_type(8)));
typedef float f32x4 __attribute__((ext_vector_type(4)));

__device__ __forceinline__ float rcp_(float x){ return __builtin_amdgcn_rcpf(x); }
__device__ __forceinline__ float sigmoidf_(float x){ return rcp_(1.0f + __expf(-x)); }
__device__ __forceinline__ float tanhf_(float x){ return fmaf(-2.0f, rcp_(1.0f + __expf(2.0f*x)), 1.0f); }

// ---------------------------------------------------------------------------
// Kernel 1: repack W_ih/W_hh into MFMA B-fragment order (as before), PLUS
// emit the GCN projection matrix W2 (block-diag [Ws|Wc] + bias row k=16)
// directly in B-fragment layout: w2frag[(nt*64+lane)*8 + e] =
// W2[k=8*(lane>>4)+e][f=16*nt+(lane&15)].
// ---------------------------------------------------------------------------
__global__ __launch_bounds__(256) void prep_kernel(const float* __restrict__ W_ih,
                                                   const float* __restrict__ W_hh,
                                                   const float* __restrict__ Wc,
                                                   const float* __restrict__ bc,
                                                   const float* __restrict__ Ws,
                                                   const float* __restrict__ bs,
                                                   _Float16* __restrict__ wfrag,
                                                   _Float16* __restrict__ w2frag){
  int gid = blockIdx.x*256 + threadIdx.x;   // [0, 16384)
  if (gid < 512){
    int nt = gid >> 6, lane = gid & 63;
    int kq = lane >> 4, c = lane & 15;
    _Float16* dst2 = w2frag + (size_t)(nt*64 + lane)*8;
    #pragma unroll
    for (int e = 0; e < 8; e++){
      int k = 8*kq + e;
      int f = 16*nt + c;
      float v = 0.f;
      if (f < 64){
        if (k < 8) v = Ws[f*8 + k];
        else if (k == 16) v = bs[f];
      } else {
        if (k >= 8 && k < 16) v = Wc[(f-64)*8 + (k-8)];
        else if (k == 16) v = bc[f-64];
      }
      dst2[e] = (_Float16)v;
    }
  }
  int w    = gid >> 11;
  int i    = (gid >> 6) & 31;
  int lane = gid & 63;
  int src = i >> 4, kk = (i >> 2) & 3, cti = i & 3;
  int j = 16*w + 128*cti + (lane & 15);
  int kbase = 32*kk + 8*(lane >> 4);
  const float* W = src ? W_hh : W_ih;
  _Float16* dst = wfrag + (size_t)(((w*32 + i)*64 + lane) * 8);
  #pragma unroll
  for (int e = 0; e < 8; e++) dst[e] = (_Float16)W[j*128 + kbase + e];
}

// ---------------------------------------------------------------------------
// Kernel 2: GCN v3 — one WAVE per (b,t) slice; 512 blocks x 256 thr.
// Pairwise d^2 via Gram MFMA: d2 = |xm|^2+|xn|^2-2*(X X^T), replacing the
// 64-iter readlane loop (16 MFMAs; A/B frags are the SAME 4 registers by
// symmetry). W2 fragments read pre-packed from prep. No __syncthreads at all
// (wave-independent; As/zs/ns are per-wave LDS).
// ---------------------------------------------------------------------------
__global__ __launch_bounds__(256) void gcn3_kernel(const float* __restrict__ x,
    const _Float16* __restrict__ w2frag, _Float16* __restrict__ feat){
  __shared__ _Float16 As16[4][64*72];   // per-wave unnormalized w, padded
  __shared__ _Float16 zs16[4][64*40];   // per-wave z = [x | y | 1@16 | 0]
  __shared__ float    ns16[4][64];      // per-wave |x_n|^2

  int tid = threadIdx.x;
  int wav = tid >> 6, lane = tid & 63;
  int slice = blockIdx.x*4 + wav;       // 0..2047
  int b = slice >> 7, t = slice & 127;
  int c = lane & 15, kq = lane >> 4;

  _Float16* As_w = &As16[wav][0];
  _Float16* zs_w = &zs16[wav][0];
  float*    ns_w = &ns16[wav][0];

  // per-lane x row (f32); zs row = [x(0-7) | zeros(8-31)]; norm to LDS
  const float* xrow = x + ((size_t)(b*64 + lane)*128 + t)*8;
  float4 xlo = *(const float4*)xrow;
  float4 xhi = *(const float4*)(xrow + 4);
  float xr[8] = {xlo.x, xlo.y, xlo.z, xlo.w, xhi.x, xhi.y, xhi.z, xhi.w};
  {
    half8 hx;
    float nrm = 0.f;
    #pragma unroll
    for (int d = 0; d < 8; d++){ hx[d] = (_Float16)xr[d]; nrm = fmaf(xr[d], xr[d], nrm); }
    half8 h0 = (half8){0,0,0,0,0,0,0,0};
    *(half8*)(zs_w + lane*40)      = hx;
    *(half8*)(zs_w + lane*40 + 8)  = h0;
    *(half8*)(zs_w + lane*40 + 16) = h0;
    *(half8*)(zs_w + lane*40 + 24) = h0;
    ns_w[lane] = nrm;
  }

  // projection B-fragments: pre-packed, coalesced
  half8 wfr[8];
  #pragma unroll
  for (int nt = 0; nt < 8; nt++)
    wfr[nt] = *(const half8*)(w2frag + (size_t)(nt*64 + lane)*8);

  // Gram fragments: ga[q] covers nodes 16q+c, k=8kq..+7 (cols 8-31 zero).
  // Same registers serve as A (rows) and B (cols) by symmetry.
  half8 ga[4];
  #pragma unroll
  for (int q = 0; q < 4; q++)
    ga[q] = *(const half8*)(zs_w + (16*q + c)*40 + 8*kq);

  // ga now in regs; set bias-ones col 16 (read later by proj az, kq=2)
  asm volatile("s_waitcnt lgkmcnt(0)" ::: "memory");
  {
    half8 h1 = (half8){(_Float16)1.f,0,0,0,0,0,0,0};
    *(half8*)(zs_w + lane*40 + 16) = h1;
  }

  // A@x B-fragments (x_aug cols: 0-7 = x, col 8 = ones for rowsum)
  half8 bx0, bx1;
  {
    half8 t0, t1;
    #pragma unroll
    for (int e = 0; e < 8; e++){
      t0[e] = zs_w[(8*kq + e)*40 + c];
      t1[e] = zs_w[(32 + 8*kq + e)*40 + c];
    }
    half8 h1a = (half8){(_Float16)1.f,(_Float16)1.f,(_Float16)1.f,(_Float16)1.f,
                        (_Float16)1.f,(_Float16)1.f,(_Float16)1.f,(_Float16)1.f};
    bx0 = (c == 8) ? h1a : t0;
    bx1 = (c == 8) ? h1a : t1;
  }

  // norms: nm[mt][e] = |x_{16mt+4kq+e}|^2 (one b128 per mt); nn[nt] = |x_{16nt+c}|^2
  f32x4 nm[4];
  float nn[4];
  #pragma unroll
  for (int q = 0; q < 4; q++){
    nm[q] = *(const f32x4*)(ns_w + 16*q + 4*kq);
    nn[q] = ns_w[16*q + c];
  }

  const f32x4 zero4 = (f32x4){0.f,0.f,0.f,0.f};
  int ediag = c - 4*kq;   // diag element index (valid when 0..3)

  // Gram -> w = rsqrt(d2) (diag 0) -> As (f16)
  #pragma unroll
  for (int mt = 0; mt < 4; mt++){
    #pragma unroll
    for (int nt = 0; nt < 4; nt++){
      f32x4 g = __builtin_amdgcn_mfma_f32_16x16x32_f16(ga[mt], ga[nt], zero4, 0,0,0);
      #pragma unroll
      for (int e = 0; e < 4; e++){
        float d2 = nm[mt][e] + nn[nt] - 2.0f*g[e];
        float wv = __frsqrt_rn(fmaxf(d2, 1e-12f));
        if (mt == nt && e == ediag) wv = 0.f;
        As_w[(16*mt + 4*kq + e)*72 + 16*nt + c] = (_Float16)wv;
      }
    }
  }

  // A@x + row-normalize -> y into zs cols 8-15
  #pragma unroll
  for (int mt = 0; mt < 4; mt++){
    half8 aa0 = *(const half8*)(As_w + (16*mt + c)*72 + 8*kq);
    half8 aa1 = *(const half8*)(As_w + (16*mt + c)*72 + 32 + 8*kq);
    f32x4 cax = __builtin_amdgcn_mfma_f32_16x16x32_f16(aa0, bx0, zero4, 0,0,0);
    cax = __builtin_amdgcn_mfma_f32_16x16x32_f16(aa1, bx1, cax, 0,0,0);
    int bidx = ((lane & 48) | 8) << 2;   // pull rowsum from lane (16kq+8)
    #pragma unroll
    for (int e = 0; e < 4; e++){
      float rs = __int_as_float(__builtin_amdgcn_ds_bpermute(bidx, __float_as_int(cax[e])));
      float yv = cax[e] * rcp_(fmaxf(rs, 1e-12f));
      if (c < 8) zs_w[(16*mt + 4*kq + e)*40 + 8 + c] = (_Float16)yv;
    }
  }

  // concat-projection (K=32: x|y|bias-ones) + SELU + f16 store
  #pragma unroll
  for (int mt = 0; mt < 4; mt++){
    half8 az = *(const half8*)(zs_w + (16*mt + c)*40 + 8*kq);
    #pragma unroll
    for (int nt = 0; nt < 8; nt++){
      f32x4 pc = __builtin_amdgcn_mfma_f32_16x16x32_f16(az, wfr[nt], zero4, 0,0,0);
      #pragma unroll
      for (int e = 0; e < 4; e++){
        float v = pc[e];
        v = (v > 0.f) ? 1.0507009873554805f*v
                      : 1.7580993408473766f*(__expf(v) - 1.0f);
        feat[((size_t)t*1024 + (size_t)b*64 + 16*mt + 4*kq + e)*128 + 16*nt + c] = (_Float16)v;
      }
    }
  }
}

// ---------------------------------------------------------------------------
// Kernel 3: persistent fused LSTM (round-5/9 proven version, verbatim).
// 256 blocks x 512 thr, 4 samples/block; x-gates built 4 steps at a time in
// one M=16 tile; h-GEMM 16 MFMA/wave/step; 1 raw s_barrier/step.
// Register-minimal form: single K=128 chains + SEL cndmask select — proven
// faster than K-split/SEL-free variants (r10: those spill at 128 VGPR cap).
// ---------------------------------------------------------------------------
__global__ __launch_bounds__(512, 2) void lstm3_kernel(
    const _Float16* __restrict__ wfrag, const _Float16* __restrict__ feat,
    const float* __restrict__ b_ih, const float* __restrict__ b_hh,
    float* __restrict__ out){
  int tid = threadIdx.x;
  int w = tid >> 6, l = tid & 63;
  int blk = blockIdx.x;            // 0..255
  int r = l & 15, kq = l >> 4;
  __shared__ _Float16 h_lds[2][544];   // [parity][sample*134 + hidden]

  half8 bf[32];
  const _Float16* wb = wfrag + (size_t)w*(32*64*8);
  #pragma unroll
  for (int i = 0; i < 32; i++)
    bf[i] = *(const half8*)(wb + (size_t)(i*64 + l)*8);

  f32x4 biasx4[4];
  #pragma unroll
  for (int cti = 0; cti < 4; cti++){
    int j = 16*w + 128*cti + r;
    float bv = b_ih[j] + b_hh[j];
    biasx4[cti] = (f32x4){bv, bv, bv, bv};
  }

  for (int idx = tid; idx < 544; idx += 512) h_lds[0][idx] = (_Float16)0.f;

  float cc = 0.f, hlast = 0.f;
  const f32x4 zero4 = (f32x4){0.f,0.f,0.f,0.f};

  const size_t arow_s = (size_t)(blk*4 + (r >> 2));
  const int atl = r & 3;
  const int habase = (r & 3)*134 + 8*kq;

  half8 afA[4], afB[4];
  f32x4 accxA[4], accxB[4];

#define LOADAF(AF, G) {                                                       \
    int gg = (G) > 31 ? 31 : (G);                                             \
    const _Float16* fb = feat + ((size_t)(4*gg + atl)*1024 + arow_s)*128 + 8*kq; \
    AF[0] = *(const half8*)(fb);                                              \
    AF[1] = *(const half8*)(fb + 32);                                         \
    AF[2] = *(const half8*)(fb + 64);                                         \
    AF[3] = *(const half8*)(fb + 96);                                         \
  }

  LOADAF(afA, 0)
  #pragma unroll
  for (int cti = 0; cti < 4; cti++)
    accxA[cti] = __builtin_amdgcn_mfma_f32_16x16x32_f16(afA[0], bf[cti], biasx4[cti], 0,0,0);
  #pragma unroll
  for (int kk = 1; kk < 4; kk++)
    #pragma unroll
    for (int cti = 0; cti < 4; cti++)
      accxA[cti] = __builtin_amdgcn_mfma_f32_16x16x32_f16(afA[kk], bf[kk*4+cti], accxA[cti], 0,0,0);
  LOADAF(afB, 1)
  LOADAF(afA, 2)
  __syncthreads();

#define SEL(A) ((kq & 2) ? ((kq & 1) ? A[3] : A[2]) : ((kq & 1) ? A[1] : A[0]))

#define STEP3(TL, ACCU, ACCB, AFB_, GN)                                       \
  {                                                                           \
    half8 ha[4];                                                              \
    _Pragma("unroll")                                                         \
    for (int kk = 0; kk < 4; kk++)                                            \
      ha[kk] = *(const half8*)(&h_lds[(TL)&1][habase + 32*kk]);               \
    f32x4 acc0, acc1, acc2, acc3;                                             \
    acc0 = __builtin_amdgcn_mfma_f32_16x16x32_f16(ha[0], bf[16], zero4, 0,0,0); \
    acc1 = __builtin_amdgcn_mfma_f32_16x16x32_f16(ha[0], bf[17], zero4, 0,0,0); \
    acc2 = __builtin_amdgcn_mfma_f32_16x16x32_f16(ha[0], bf[18], zero4, 0,0,0); \
    acc3 = __builtin_amdgcn_mfma_f32_16x16x32_f16(ha[0], bf[19], zero4, 0,0,0); \
    _Pragma("unroll")                                                         \
    for (int kk = 1; kk < 4; kk++){                                           \
      acc0 = __builtin_amdgcn_mfma_f32_16x16x32_f16(ha[kk], bf[16+kk*4+0], acc0, 0,0,0); \
      acc1 = __builtin_amdgcn_mfma_f32_16x16x32_f16(ha[kk], bf[16+kk*4+1], acc1, 0,0,0); \
      acc2 = __builtin_amdgcn_mfma_f32_16x16x32_f16(ha[kk], bf[16+kk*4+2], acc2, 0,0,0); \
      acc3 = __builtin_amdgcn_mfma_f32_16x16x32_f16(ha[kk], bf[16+kk*4+3], acc3, 0,0,0); \
    }                                                                         \
    _Pragma("unroll")                                                         \
    for (int cti = 0; cti < 4; cti++){                                        \
      if ((TL) == 0)                                                          \
        ACCB[cti] = __builtin_amdgcn_mfma_f32_16x16x32_f16(AFB_[0], bf[cti], biasx4[cti], 0,0,0); \
      else                                                                    \
        ACCB[cti] = __builtin_amdgcn_mfma_f32_16x16x32_f16(AFB_[(TL)], bf[(TL)*4+cti], ACCB[cti], 0,0,0); \
    }                                                                         \
    if ((TL) == 3) LOADAF(AFB_, GN)                                           \
    float g0_ = SEL(acc0) + ACCU[0][(TL)];                                    \
    float g1_ = SEL(acc1) + ACCU[1][(TL)];                                    \
    float g2_ = SEL(acc2) + ACCU[2][(TL)];                                    \
    float g3_ = SEL(acc3) + ACCU[3][(TL)];                                    \
    float c_ = fmaf(sigmoidf_(g1_), cc, sigmoidf_(g0_)*tanhf_(g2_));          \
    cc = c_;                                                                  \
    float h_ = sigmoidf_(g3_)*tanhf_(c_);                                     \
    h_lds[1-((TL)&1)][kq*134 + 16*w + r] = (_Float16)h_;                      \
    if ((TL) == 3 && (GN) == 32) hlast = h_;                                  \
    asm volatile("s_waitcnt lgkmcnt(0)" ::: "memory");                        \
    __builtin_amdgcn_s_barrier();                                             \
  }

  for (int i = 0; i < 15; ++i){
    STEP3(0, accxA, accxB, afB, 0)
    STEP3(1, accxA, accxB, afB, 0)
    STEP3(2, accxA, accxB, afB, 0)
    STEP3(3, accxA, accxB, afB, 2*i+3)
    STEP3(0, accxB, accxA, afA, 0)
    STEP3(1, accxB, accxA, afA, 0)
    STEP3(2, accxB, accxA, afA, 0)
    STEP3(3, accxB, accxA, afA, 2*i+4)
  }
  STEP3(0, accxA, accxB, afB, 0)
  STEP3(1, accxA, accxB, afB, 0)
  STEP3(2, accxA, accxB, afB, 0)
  STEP3(3, accxA, accxB, afB, 33)
  STEP3(0, accxB, accxA, afA, 0)
  STEP3(1, accxB, accxA, afA, 0)
  STEP3(2, accxB, accxA, afA, 0)
  STEP3(3, accxB, accxA, afA, 32)   // t = 127: capture hlast
#undef STEP3
#undef SEL
#undef LOADAF

  out[((size_t)blk*4 + kq)*128 + 16*w + r] = hlast;
}

// ---------------------------------------------------------------------------
extern "C" void kernel_launch(void* const* d_in, const int* in_sizes, int n_in,
                              void* d_out, int out_size, void* d_ws, size_t ws_size,
                              hipStream_t stream) {
  const float* x    = (const float*)d_in[0];
  const float* Wc   = (const float*)d_in[3];
  const float* bc   = (const float*)d_in[4];
  const float* Ws   = (const float*)d_in[5];
  const float* bs   = (const float*)d_in[6];
  const float* W_ih = (const float*)d_in[7];
  const float* W_hh = (const float*)d_in[8];
  const float* b_ih = (const float*)d_in[9];
  const float* b_hh = (const float*)d_in[10];
  float* out = (float*)d_out;

  // ws: [0,256KB) wfrag | [262144,+8KB) w2frag | [270336, +33.5MB) feat
  _Float16* wfrag  = (_Float16*)d_ws;
  _Float16* w2frag = (_Float16*)((char*)d_ws + 262144);
  _Float16* feat   = (_Float16*)((char*)d_ws + 270336);

  prep_kernel<<<64, 256, 0, stream>>>(W_ih, W_hh, Wc, bc, Ws, bs, wfrag, w2frag);
  gcn3_kernel<<<512, 256, 0, stream>>>(x, w2frag, feat);
  lstm3_kernel<<<256, 512, 0, stream>>>(wfrag, feat, b_ih, b_hh, out);
}

// Round 12
// 101.990 us; speedup vs baseline: 1.0838x; 1.0148x over previous
//
#include <hip/hip_runtime.h>
#include <hip/hip_bf16.h>

// Problem constants: B=16, N=64, T=128, D=8, N_EMB=64, N_H=128, BN=1024,
// F_in=128, gates=512.

typedef _Float16 half8 __attribute__((ext_vector_type(8)));
typedef float f32x4 __attribute__((ext_vector_type(4)));

__device__ __forceinline__ float rcp_(float x){ return __builtin_amdgcn_rcpf(x); }
__device__ __forceinline__ float sigmoidf_(float x){ return rcp_(1.0f + __expf(-x)); }
__device__ __forceinline__ float tanhf_(float x){ return fmaf(-2.0f, rcp_(1.0f + __expf(2.0f*x)), 1.0f); }

// ---------------------------------------------------------------------------
// Kernel 1: repack W_ih/W_hh into MFMA B-fragment order (as before), PLUS
// emit the GCN projection matrix W2 (block-diag [Ws|Wc] + bias row k=16)
// directly in B-fragment layout: w2frag[(nt*64+lane)*8 + e] =
// W2[k=8*(lane>>4)+e][f=16*nt+(lane&15)].
// ---------------------------------------------------------------------------
__global__ __launch_bounds__(256) void prep_kernel(const float* __restrict__ W_ih,
                                                   const float* __restrict__ W_hh,
                                                   const float* __restrict__ Wc,
                                                   const float* __restrict__ bc,
                                                   const float* __restrict__ Ws,
                                                   const float* __restrict__ bs,
                                                   _Float16* __restrict__ wfrag,
                                                   _Float16* __restrict__ w2frag){
  int gid = blockIdx.x*256 + threadIdx.x;   // [0, 16384)
  if (gid < 512){
    int nt = gid >> 6, lane = gid & 63;
    int kq = lane >> 4, c = lane & 15;
    _Float16* dst2 = w2frag + (size_t)(nt*64 + lane)*8;
    #pragma unroll
    for (int e = 0; e < 8; e++){
      int k = 8*kq + e;
      int f = 16*nt + c;
      float v = 0.f;
      if (f < 64){
        if (k < 8) v = Ws[f*8 + k];
        else if (k == 16) v = bs[f];
      } else {
        if (k >= 8 && k < 16) v = Wc[(f-64)*8 + (k-8)];
        else if (k == 16) v = bc[f-64];
      }
      dst2[e] = (_Float16)v;
    }
  }
  int w    = gid >> 11;
  int i    = (gid >> 6) & 31;
  int lane = gid & 63;
  int src = i >> 4, kk = (i >> 2) & 3, cti = i & 3;
  int j = 16*w + 128*cti + (lane & 15);
  int kbase = 32*kk + 8*(lane >> 4);
  const float* W = src ? W_hh : W_ih;
  _Float16* dst = wfrag + (size_t)(((w*32 + i)*64 + lane) * 8);
  #pragma unroll
  for (int e = 0; e < 8; e++) dst[e] = (_Float16)W[j*128 + kbase + e];
}

// ---------------------------------------------------------------------------
// Kernel 2: GCN v3 (round-9 proven, verbatim). One WAVE per (b,t) slice.
// ---------------------------------------------------------------------------
__global__ __launch_bounds__(256) void gcn3_kernel(const float* __restrict__ x,
    const _Float16* __restrict__ w2frag, _Float16* __restrict__ feat){
  __shared__ _Float16 As16[4][64*72];   // per-wave unnormalized w, padded
  __shared__ _Float16 zs16[4][64*40];   // per-wave z = [x | y | 1@16 | 0]
  __shared__ float    ns16[4][64];      // per-wave |x_n|^2

  int tid = threadIdx.x;
  int wav = tid >> 6, lane = tid & 63;
  int slice = blockIdx.x*4 + wav;       // 0..2047
  int b = slice >> 7, t = slice & 127;
  int c = lane & 15, kq = lane >> 4;

  _Float16* As_w = &As16[wav][0];
  _Float16* zs_w = &zs16[wav][0];
  float*    ns_w = &ns16[wav][0];

  const float* xrow = x + ((size_t)(b*64 + lane)*128 + t)*8;
  float4 xlo = *(const float4*)xrow;
  float4 xhi = *(const float4*)(xrow + 4);
  float xr[8] = {xlo.x, xlo.y, xlo.z, xlo.w, xhi.x, xhi.y, xhi.z, xhi.w};
  {
    half8 hx;
    float nrm = 0.f;
    #pragma unroll
    for (int d = 0; d < 8; d++){ hx[d] = (_Float16)xr[d]; nrm = fmaf(xr[d], xr[d], nrm); }
    half8 h0 = (half8){0,0,0,0,0,0,0,0};
    *(half8*)(zs_w + lane*40)      = hx;
    *(half8*)(zs_w + lane*40 + 8)  = h0;
    *(half8*)(zs_w + lane*40 + 16) = h0;
    *(half8*)(zs_w + lane*40 + 24) = h0;
    ns_w[lane] = nrm;
  }

  half8 wfr[8];
  #pragma unroll
  for (int nt = 0; nt < 8; nt++)
    wfr[nt] = *(const half8*)(w2frag + (size_t)(nt*64 + lane)*8);

  half8 ga[4];
  #pragma unroll
  for (int q = 0; q < 4; q++)
    ga[q] = *(const half8*)(zs_w + (16*q + c)*40 + 8*kq);

  asm volatile("s_waitcnt lgkmcnt(0)" ::: "memory");
  {
    half8 h1 = (half8){(_Float16)1.f,0,0,0,0,0,0,0};
    *(half8*)(zs_w + lane*40 + 16) = h1;
  }

  half8 bx0, bx1;
  {
    half8 t0, t1;
    #pragma unroll
    for (int e = 0; e < 8; e++){
      t0[e] = zs_w[(8*kq + e)*40 + c];
      t1[e] = zs_w[(32 + 8*kq + e)*40 + c];
    }
    half8 h1a = (half8){(_Float16)1.f,(_Float16)1.f,(_Float16)1.f,(_Float16)1.f,
                        (_Float16)1.f,(_Float16)1.f,(_Float16)1.f,(_Float16)1.f};
    bx0 = (c == 8) ? h1a : t0;
    bx1 = (c == 8) ? h1a : t1;
  }

  f32x4 nm[4];
  float nn[4];
  #pragma unroll
  for (int q = 0; q < 4; q++){
    nm[q] = *(const f32x4*)(ns_w + 16*q + 4*kq);
    nn[q] = ns_w[16*q + c];
  }

  const f32x4 zero4 = (f32x4){0.f,0.f,0.f,0.f};
  int ediag = c - 4*kq;   // diag element index (valid when 0..3)

  #pragma unroll
  for (int mt = 0; mt < 4; mt++){
    #pragma unroll
    for (int nt = 0; nt < 4; nt++){
      f32x4 g = __builtin_amdgcn_mfma_f32_16x16x32_f16(ga[mt], ga[nt], zero4, 0,0,0);
      #pragma unroll
      for (int e = 0; e < 4; e++){
        float d2 = nm[mt][e] + nn[nt] - 2.0f*g[e];
        float wv = __frsqrt_rn(fmaxf(d2, 1e-12f));
        if (mt == nt && e == ediag) wv = 0.f;
        As_w[(16*mt + 4*kq + e)*72 + 16*nt + c] = (_Float16)wv;
      }
    }
  }

  #pragma unroll
  for (int mt = 0; mt < 4; mt++){
    half8 aa0 = *(const half8*)(As_w + (16*mt + c)*72 + 8*kq);
    half8 aa1 = *(const half8*)(As_w + (16*mt + c)*72 + 32 + 8*kq);
    f32x4 cax = __builtin_amdgcn_mfma_f32_16x16x32_f16(aa0, bx0, zero4, 0,0,0);
    cax = __builtin_amdgcn_mfma_f32_16x16x32_f16(aa1, bx1, cax, 0,0,0);
    int bidx = ((lane & 48) | 8) << 2;   // pull rowsum from lane (16kq+8)
    #pragma unroll
    for (int e = 0; e < 4; e++){
      float rs = __int_as_float(__builtin_amdgcn_ds_bpermute(bidx, __float_as_int(cax[e])));
      float yv = cax[e] * rcp_(fmaxf(rs, 1e-12f));
      if (c < 8) zs_w[(16*mt + 4*kq + e)*40 + 8 + c] = (_Float16)yv;
    }
  }

  #pragma unroll
  for (int mt = 0; mt < 4; mt++){
    half8 az = *(const half8*)(zs_w + (16*mt + c)*40 + 8*kq);
    #pragma unroll
    for (int nt = 0; nt < 8; nt++){
      f32x4 pc = __builtin_amdgcn_mfma_f32_16x16x32_f16(az, wfr[nt], zero4, 0,0,0);
      #pragma unroll
      for (int e = 0; e < 4; e++){
        float v = pc[e];
        v = (v > 0.f) ? 1.0507009873554805f*v
                      : 1.7580993408473766f*(__expf(v) - 1.0f);
        feat[((size_t)t*1024 + (size_t)b*64 + 16*mt + 4*kq + e)*128 + 16*nt + c] = (_Float16)v;
      }
    }
  }
}

// ---------------------------------------------------------------------------
// Kernel 3: persistent fused LSTM v3c. ONE change vs the proven round-5/9
// version: the h-GEMM A-tile rows are grouped by sample (row r -> sample
// r>>2, duplicate rows adjacent), so C rows 4kq+e all hold sample kq and the
// cell reads acc[0] directly -- SEL's 12 cndmask + 12 extra accvgpr reads
// per lane-step are gone. Register-neutral (r10's spill came from the
// bundled K-split, not this). Everything else verbatim.
// ---------------------------------------------------------------------------
__global__ __launch_bounds__(512, 2) void lstm3_kernel(
    const _Float16* __restrict__ wfrag, const _Float16* __restrict__ feat,
    const float* __restrict__ b_ih, const float* __restrict__ b_hh,
    float* __restrict__ out){
  int tid = threadIdx.x;
  int w = tid >> 6, l = tid & 63;
  int blk = blockIdx.x;            // 0..255
  int r = l & 15, kq = l >> 4;
  __shared__ _Float16 h_lds[2][544];   // [parity][sample*134 + hidden]

  half8 bf[32];
  const _Float16* wb = wfrag + (size_t)w*(32*64*8);
  #pragma unroll
  for (int i = 0; i < 32; i++)
    bf[i] = *(const half8*)(wb + (size_t)(i*64 + l)*8);

  f32x4 biasx4[4];
  #pragma unroll
  for (int cti = 0; cti < 4; cti++){
    int j = 16*w + 128*cti + r;
    float bv = b_ih[j] + b_hh[j];
    biasx4[cti] = (f32x4){bv, bv, bv, bv};
  }

  for (int idx = tid; idx < 544; idx += 512) h_lds[0][idx] = (_Float16)0.f;

  float cc = 0.f, hlast = 0.f;
  const f32x4 zero4 = (f32x4){0.f,0.f,0.f,0.f};

  const size_t arow_s = (size_t)(blk*4 + (r >> 2));
  const int atl = r & 3;
  // h A-tile rows grouped by sample: row r -> sample r>>2 (was r&3)
  const int habase = (r >> 2)*134 + 8*kq;

  half8 afA[4], afB[4];
  f32x4 accxA[4], accxB[4];

#define LOADAF(AF, G) {                                                       \
    int gg = (G) > 31 ? 31 : (G);                                             \
    const _Float16* fb = feat + ((size_t)(4*gg + atl)*1024 + arow_s)*128 + 8*kq; \
    AF[0] = *(const half8*)(fb);                                              \
    AF[1] = *(const half8*)(fb + 32);                                         \
    AF[2] = *(const half8*)(fb + 64);                                         \
    AF[3] = *(const half8*)(fb + 96);                                         \
  }

  LOADAF(afA, 0)
  #pragma unroll
  for (int cti = 0; cti < 4; cti++)
    accxA[cti] = __builtin_amdgcn_mfma_f32_16x16x32_f16(afA[0], bf[cti], biasx4[cti], 0,0,0);
  #pragma unroll
  for (int kk = 1; kk < 4; kk++)
    #pragma unroll
    for (int cti = 0; cti < 4; cti++)
      accxA[cti] = __builtin_amdgcn_mfma_f32_16x16x32_f16(afA[kk], bf[kk*4+cti], accxA[cti], 0,0,0);
  LOADAF(afB, 1)
  LOADAF(afA, 2)
  __syncthreads();

#define STEP3(TL, ACCU, ACCB, AFB_, GN)                                       \
  {                                                                           \
    half8 ha[4];                                                              \
    _Pragma("unroll")                                                         \
    for (int kk = 0; kk < 4; kk++)                                            \
      ha[kk] = *(const half8*)(&h_lds[(TL)&1][habase + 32*kk]);               \
    f32x4 acc0, acc1, acc2, acc3;                                             \
    acc0 = __builtin_amdgcn_mfma_f32_16x16x32_f16(ha[0], bf[16], zero4, 0,0,0); \
    acc1 = __builtin_amdgcn_mfma_f32_16x16x32_f16(ha[0], bf[17], zero4, 0,0,0); \
    acc2 = __builtin_amdgcn_mfma_f32_16x16x32_f16(ha[0], bf[18], zero4, 0,0,0); \
    acc3 = __builtin_amdgcn_mfma_f32_16x16x32_f16(ha[0], bf[19], zero4, 0,0,0); \
    _Pragma("unroll")                                                         \
    for (int kk = 1; kk < 4; kk++){                                           \
      acc0 = __builtin_amdgcn_mfma_f32_16x16x32_f16(ha[kk], bf[16+kk*4+0], acc0, 0,0,0); \
      acc1 = __builtin_amdgcn_mfma_f32_16x16x32_f16(ha[kk], bf[16+kk*4+1], acc1, 0,0,0); \
      acc2 = __builtin_amdgcn_mfma_f32_16x16x32_f16(ha[kk], bf[16+kk*4+2], acc2, 0,0,0); \
      acc3 = __builtin_amdgcn_mfma_f32_16x16x32_f16(ha[kk], bf[16+kk*4+3], acc3, 0,0,0); \
    }                                                                         \
    _Pragma("unroll")                                                         \
    for (int cti = 0; cti < 4; cti++){                                        \
      if ((TL) == 0)                                                          \
        ACCB[cti] = __builtin_amdgcn_mfma_f32_16x16x32_f16(AFB_[0], bf[cti], biasx4[cti], 0,0,0); \
      else                                                                    \
        ACCB[cti] = __builtin_amdgcn_mfma_f32_16x16x32_f16(AFB_[(TL)], bf[(TL)*4+cti], ACCB[cti], 0,0,0); \
    }                                                                         \
    if ((TL) == 3) LOADAF(AFB_, GN)                                           \
    float g0_ = acc0[0] + ACCU[0][(TL)];                                      \
    float g1_ = acc1[0] + ACCU[1][(TL)];                                      \
    float g2_ = acc2[0] + ACCU[2][(TL)];                                      \
    float g3_ = acc3[0] + ACCU[3][(TL)];                                      \
    float c_ = fmaf(sigmoidf_(g1_), cc, sigmoidf_(g0_)*tanhf_(g2_));          \
    cc = c_;                                                                  \
    float h_ = sigmoidf_(g3_)*tanhf_(c_);                                     \
    h_lds[1-((TL)&1)][kq*134 + 16*w + r] = (_Float16)h_;                      \
    if ((TL) == 3 && (GN) == 32) hlast = h_;                                  \
    asm volatile("s_waitcnt lgkmcnt(0)" ::: "memory");                        \
    __builtin_amdgcn_s_barrier();                                             \
  }

  for (int i = 0; i < 15; ++i){
    STEP3(0, accxA, accxB, afB, 0)
    STEP3(1, accxA, accxB, afB, 0)
    STEP3(2, accxA, accxB, afB, 0)
    STEP3(3, accxA, accxB, afB, 2*i+3)
    STEP3(0, accxB, accxA, afA, 0)
    STEP3(1, accxB, accxA, afA, 0)
    STEP3(2, accxB, accxA, afA, 0)
    STEP3(3, accxB, accxA, afA, 2*i+4)
  }
  STEP3(0, accxA, accxB, afB, 0)
  STEP3(1, accxA, accxB, afB, 0)
  STEP3(2, accxA, accxB, afB, 0)
  STEP3(3, accxA, accxB, afB, 33)
  STEP3(0, accxB, accxA, afA, 0)
  STEP3(1, accxB, accxA, afA, 0)
  STEP3(2, accxB, accxA, afA, 0)
  STEP3(3, accxB, accxA, afA, 32)   // t = 127: capture hlast
#undef STEP3
#undef LOADAF

  out[((size_t)blk*4 + kq)*128 + 16*w + r] = hlast;
}

// ---------------------------------------------------------------------------
extern "C" void kernel_launch(void* const* d_in, const int* in_sizes, int n_in,
                              void* d_out, int out_size, void* d_ws, size_t ws_size,
                              hipStream_t stream) {
  const float* x    = (const float*)d_in[0];
  const float* Wc   = (const float*)d_in[3];
  const float* bc   = (const float*)d_in[4];
  const float* Ws   = (const float*)d_in[5];
  const float* bs   = (const float*)d_in[6];
  const float* W_ih = (const float*)d_in[7];
  const float* W_hh = (const float*)d_in[8];
  const float* b_ih = (const float*)d_in[9];
  const float* b_hh = (const float*)d_in[10];
  float* out = (float*)d_out;

  // ws: [0,256KB) wfrag | [262144,+8KB) w2frag | [270336, +33.5MB) feat
  _Float16* wfrag  = (_Float16*)d_ws;
  _Float16* w2frag = (_Float16*)((char*)d_ws + 262144);
  _Float16* feat   = (_Float16*)((char*)d_ws + 270336);

  prep_kernel<<<64, 256, 0, stream>>>(W_ih, W_hh, Wc, bc, Ws, bs, wfrag, w2frag);
  gcn3_kernel<<<512, 256, 0, stream>>>(x, w2frag, feat);
  lstm3_kernel<<<256, 512, 0, stream>>>(wfrag, feat, b_ih, b_hh, out);
}